// Round 8
// baseline (299.320 us; speedup 1.0000x reference)
//
#include <hip/hip_runtime.h>

typedef __bf16 bf16;
typedef __attribute__((ext_vector_type(8))) __bf16 bf16x8;
typedef __attribute__((ext_vector_type(4))) __bf16 bf16x4;
typedef __attribute__((ext_vector_type(4))) float f32x4;
typedef __attribute__((ext_vector_type(4))) int i32x4;

#define S_LEN 2048
#define DM 1024
#define NB 4

// Raw barrier discipline (round 7, verified): no compiler-forced vmcnt(0)
// drain at barriers, so prefetch loads stay in flight across them.
#define LGKM0 asm volatile("s_waitcnt lgkmcnt(0)" ::: "memory")
#define BAR   asm volatile("s_barrier" ::: "memory")

// =====================================================================
// Register-staged 128x128 NT GEMM tile, BK=64, 4 waves (2x2), single
// 32 KB LDS buffer. Round-7 post-mortem: global_load_lds delivery caps at
// ~22 B/cyc/CU in every structure (r4/r6/r7/m97 all plateau there), which
// bounds this tile at ~42% MfmaUtil. So stage via buffer_load -> VGPR ->
// ds_write (the hipBLASLt/AITER path): per kstep each thread prefetches
// 8x dwordx4 one full kstep ahead (compiler emits fine-grained vmcnt
// waits before the dependent ds_writes), then ds_write -> lgkm0 -> BAR ->
// ds_read frags -> MFMA. XOR swizzle (phys octet = logical ^ (row&7))
// from round 3: SQ_LDS_BANK_CONFLICT == 0; ds_write at tid*16 is 2-way
// aliased = free (m136).
// =====================================================================

__device__ __forceinline__ void mfma16(const bf16x8 (&af)[4], const bf16x8 (&bfr)[4],
                                       f32x4 (&acc)[4][4])
{
#pragma unroll
    for (int rt = 0; rt < 4; rt++)
#pragma unroll
        for (int ct = 0; ct < 4; ct++)
            acc[rt][ct] = __builtin_amdgcn_mfma_f32_16x16x32_bf16(
                af[rt], bfr[ct], acc[rt][ct], 0, 0, 0);
}

// A: 128 rows x K (row-major, lda elems); B: 128 rows x K (row-major, ldb).
__device__ __forceinline__ void gemm_tile(
    const bf16* __restrict__ A, int lda,
    const bf16* __restrict__ B, int ldb,
    int kSteps, char* smem, f32x4 (&acc)[4][4])
{
    char* sA = smem;
    char* sB = smem + 16384;
    const int tid = threadIdx.x;
    const int w = tid >> 6, lane = tid & 63;
    const int quad = lane >> 4, l16 = lane & 15;
    const int wr = w >> 1, wc = w & 1;

#pragma unroll
    for (int i = 0; i < 4; i++)
#pragma unroll
        for (int j = 0; j < 4; j++) acc[i][j] = f32x4{0.f, 0.f, 0.f, 0.f};

    // staging map (round-3, verified): thread covers rows srow+32i, swizzled
    // source octet (sc8 ^ (srow&7)); LDS linear slot = i*4096 + tid*16.
    const int srow = tid >> 3;
    const int sc8  = tid & 7;
    const int srcCol = (sc8 ^ (srow & 7)) * 16;
    const char* aG = (const char*)(A + (size_t)srow * lda) + srcCol;
    const char* bG = (const char*)(B + (size_t)srow * ldb) + srcCol;
    const size_t aRow32 = (size_t)lda * 64;   // 32 rows * lda * 2B
    const size_t bRow32 = (size_t)ldb * 64;
    const int swz = l16 & 7;

    i32x4 rA[4], rB[4];
    // prologue: tile 0 -> regs
#pragma unroll
    for (int i = 0; i < 4; i++) {
        rA[i] = *(const i32x4*)(aG + i * aRow32);
        rB[i] = *(const i32x4*)(bG + i * bRow32);
    }

    for (int ks = 0; ks < kSteps; ks++) {
        if (ks) BAR;   // all waves done reading LDS from prev kstep
        // ds_write (compiler auto-inserts vmcnt waits for rA/rB producers)
#pragma unroll
        for (int i = 0; i < 4; i++) {
            *(i32x4*)(sA + i * 4096 + tid * 16) = rA[i];
            *(i32x4*)(sB + i * 4096 + tid * 16) = rB[i];
        }
        LGKM0;   // own writes committed
        BAR;     // all writes visible
        // prefetch tile ks+1 (stays in flight across ds_read+MFMA phase)
        if (ks + 1 < kSteps) {
            const char* aGk = aG + (size_t)(ks + 1) * 128;
            const char* bGk = bG + (size_t)(ks + 1) * 128;
#pragma unroll
            for (int i = 0; i < 4; i++) {
                rA[i] = *(const i32x4*)(aGk + i * aRow32);
                rB[i] = *(const i32x4*)(bGk + i * bRow32);
            }
        }
        // consume: per-kk to cap frag registers at 32
#pragma unroll
        for (int kk = 0; kk < 2; kk++) {
            const int col = (((kk << 2) + quad) ^ swz) << 4;
            bf16x8 af[4], bfr[4];
#pragma unroll
            for (int t = 0; t < 4; t++) {
                af[t]  = *(const bf16x8*)(sA + (wr * 64 + t * 16 + l16) * 128 + col);
                bfr[t] = *(const bf16x8*)(sB + (wc * 64 + t * 16 + l16) * 128 + col);
            }
            mfma16(af, bfr, acc);
        }
    }
}

// ---- fp32 -> bf16 cast, 3 tensors, 8 elems/thread ----
__global__ __launch_bounds__(256) void cvt3_kernel(
    const float* __restrict__ s0, const float* __restrict__ s1, const float* __restrict__ s2,
    bf16* __restrict__ d0, bf16* __restrict__ d1, bf16* __restrict__ d2)
{
    const float* src = blockIdx.y == 0 ? s0 : blockIdx.y == 1 ? s1 : s2;
    bf16* dst        = blockIdx.y == 0 ? d0 : blockIdx.y == 1 ? d1 : d2;
    size_t i = ((size_t)blockIdx.x * 256 + threadIdx.x) * 8;
    f32x4 a = *(const f32x4*)(src + i);
    f32x4 b = *(const f32x4*)(src + i + 4);
    bf16x8 o;
    o[0] = (bf16)a[0]; o[1] = (bf16)a[1]; o[2] = (bf16)a[2]; o[3] = (bf16)a[3];
    o[4] = (bf16)b[0]; o[5] = (bf16)b[1]; o[6] = (bf16)b[2]; o[7] = (bf16)b[3];
    *(bf16x8*)(dst + i) = o;
}

// ---- projection: O = E @ W^T + b ; z==2 writes Vt[b][d][s] ----
// 1-D grid 1536, XCD c (bid&7) owns M-stripe [8c,8c+8), n-fastest
// (round-4: FETCH 200 -> 58 MB).
__global__ __launch_bounds__(256, 3) void proj_kernel(
    const bf16* __restrict__ Eq, const bf16* __restrict__ Ek, const bf16* __restrict__ Ev,
    const bf16* __restrict__ Wq, const bf16* __restrict__ Wk, const bf16* __restrict__ Wv,
    const float* __restrict__ bq, const float* __restrict__ bk, const float* __restrict__ bv,
    bf16* __restrict__ Qo, bf16* __restrict__ Ko, bf16* __restrict__ Vt)
{
    __shared__ __align__(16) char smem[34816];   // GEMM 32K | epilogue 128x136 bf16
    const int bid = blockIdx.x;
    const int c = bid & 7;
    const int j = bid >> 3;          // 0..191
    const int z = j >> 6;            // 0..2
    const int r64 = j & 63;
    const int m0 = (c * 8 + (r64 >> 3)) * 128;
    const int n0 = (r64 & 7) * 128;

    const bf16* E     = z == 0 ? Eq : z == 1 ? Ek : Ev;
    const bf16* W     = z == 0 ? Wq : z == 1 ? Wk : Wv;
    const float* bias = z == 0 ? bq : z == 1 ? bk : bv;

    f32x4 acc[4][4];
    gemm_tile(E + (size_t)m0 * DM, DM, W + (size_t)n0 * DM, DM, DM / 64, smem, acc);

    const int tid = threadIdx.x;
    const int w = tid >> 6, lane = tid & 63;
    const int quad = lane >> 4, l16 = lane & 15;
    const int wr = w >> 1, wc = w & 1;
    const int nBase = n0 + wc * 64;

    float bcol[4];
#pragma unroll
    for (int ct = 0; ct < 4; ct++) bcol[ct] = bias[nBase + ct * 16 + l16];

    __syncthreads();   // safe smem reuse
    if (z < 2) {
        bf16* Tt = (bf16*)smem;   // 128 x 136 (rows 16B-aligned)
#pragma unroll
        for (int rt = 0; rt < 4; rt++)
#pragma unroll
            for (int ct = 0; ct < 4; ct++)
#pragma unroll
                for (int r = 0; r < 4; r++)
                    Tt[(wr * 64 + rt * 16 + quad * 4 + r) * 136 + wc * 64 + ct * 16 + l16]
                        = (bf16)(acc[rt][ct][r] + bcol[ct]);
        __syncthreads();
        bf16* O = z == 0 ? Qo : Ko;
        const int row = tid >> 1, half = tid & 1;
        const bf16* src = Tt + row * 136 + half * 64;
        bf16* dst = O + (size_t)(m0 + row) * DM + n0 + half * 64;
#pragma unroll
        for (int i = 0; i < 8; i++)
            *(bf16x8*)(dst + i * 8) = *(const bf16x8*)(src + i * 8);
    } else {
        // Vt[b][d][s]: lane holds 4 consecutive s for fixed d -> 8B store
        const int mBase = m0 + wr * 64;
#pragma unroll
        for (int rt = 0; rt < 4; rt++) {
            const int m = mBase + rt * 16 + quad * 4;
            const int bb = m >> 11;
            const int s  = m & 2047;
#pragma unroll
            for (int ct = 0; ct < 4; ct++) {
                const int n = nBase + ct * 16 + l16;
                bf16x4 o;
                o[0] = (bf16)(acc[rt][ct][0] + bcol[ct]);
                o[1] = (bf16)(acc[rt][ct][1] + bcol[ct]);
                o[2] = (bf16)(acc[rt][ct][2] + bcol[ct]);
                o[3] = (bf16)(acc[rt][ct][3] + bcol[ct]);
                *(bf16x4*)(Vt + ((size_t)(bb * DM + n)) * S_LEN + s) = o;
            }
        }
    }
}

// ---- P = exp(Q K^T / 32); XCD c owns kt in {c, 15-c} (causal-balanced,
// K-tile L2-resident). Repack -> coalesced stores + row sums -> atomicAdd. ----
// scores O(1): exp without max-shift is safe; softmax shift-invariant.
__global__ __launch_bounds__(256, 3) void qk_kernel(
    const bf16* __restrict__ Q, const bf16* __restrict__ K,
    const int* __restrict__ maskp, bf16* __restrict__ P, float* __restrict__ lsum)
{
    const int bid = blockIdx.x;          // 0..1023
    const int c = bid & 7;
    const int j = bid >> 3;              // 0..127
    const int b = j >> 5;
    const int jj = j & 31;
    const int kt = (jj < 16) ? c : (15 - c);
    const int qt = jj & 15;
    const bool causal = (maskp[0] != 0);
    if (causal && kt > qt) return;

    __shared__ __align__(16) char smem[34816];

    f32x4 acc[4][4];
    const bf16* Qb = Q + ((size_t)(b * S_LEN + qt * 128)) * DM;
    const bf16* Kb = K + ((size_t)(b * S_LEN + kt * 128)) * DM;
    gemm_tile(Qb, DM, Kb, DM, DM / 64, smem, acc);

    const int tid = threadIdx.x;
    const int w = tid >> 6, lane = tid & 63;
    const int quad = lane >> 4, l16 = lane & 15;
    const int wr = w >> 1, wc = w & 1;
    const float scale = 0.03125f;  // 1/sqrt(1024)

    __syncthreads();
    bf16* Pt = (bf16*)smem;   // 128 x 136
#pragma unroll
    for (int rt = 0; rt < 4; rt++)
#pragma unroll
        for (int r = 0; r < 4; r++) {
            const int rloc = wr * 64 + rt * 16 + quad * 4 + r;
            const int qg = qt * 128 + rloc;
#pragma unroll
            for (int ct = 0; ct < 4; ct++) {
                const int kg = kt * 128 + wc * 64 + ct * 16 + l16;
                float p = (!causal || kg <= qg) ? __expf(acc[rt][ct][r] * scale) : 0.0f;
                Pt[rloc * 136 + wc * 64 + ct * 16 + l16] = (bf16)p;
            }
        }
    __syncthreads();

    bf16* Pb = P + (size_t)b * S_LEN * S_LEN;
    float* lb = lsum + b * S_LEN;
    const int row = tid >> 1, half = tid & 1;
    const bf16* src = Pt + row * 136 + half * 64;
    bf16* dst = Pb + (size_t)(qt * 128 + row) * S_LEN + kt * 128 + half * 64;
    float rs = 0.0f;
#pragma unroll
    for (int i = 0; i < 8; i++) {
        bf16x8 x = *(const bf16x8*)(src + i * 8);
        *(bf16x8*)(dst + i * 8) = x;
#pragma unroll
        for (int e = 0; e < 8; e++) rs += (float)x[e];   // sum rounded values PV uses
    }
    rs += __shfl_xor(rs, 1);
    if (half == 0) atomicAdd(&lb[qt * 128 + row], rs);
}

// ---- O = (P @ Vt^T) / l ; XCD c owns dt=c (Vt stripe L2-resident), qt desc ----
__global__ __launch_bounds__(256, 3) void pv_kernel(
    const bf16* __restrict__ P, const bf16* __restrict__ Vt,
    const float* __restrict__ lsum, const int* __restrict__ maskp,
    float* __restrict__ Out)
{
    const int bid = blockIdx.x;          // 0..511
    const int dt = bid & 7;
    const int j = bid >> 3;              // 0..63
    const int b = j >> 4;
    const int qt = 15 - (j & 15);        // long blocks first
    const bool causal = (maskp[0] != 0);
    const int kSteps = causal ? (qt + 1) * 2 : (S_LEN / 64);

    __shared__ __align__(16) char smem[33792];   // GEMM 32K | O-half 64x132 f32

    f32x4 acc[4][4];
    const bf16* Pb = P + ((size_t)b * S_LEN + qt * 128) * S_LEN;
    const bf16* Vb = Vt + ((size_t)(b * DM + dt * 128)) * S_LEN;
    gemm_tile(Pb, S_LEN, Vb, S_LEN, kSteps, smem, acc);

    const int tid = threadIdx.x;
    const int w = tid >> 6, lane = tid & 63;
    const int quad = lane >> 4, l16 = lane & 15;
    const int wr = w >> 1, wc = w & 1;

    const float* lb = lsum + b * S_LEN;
    float inv[4][4];
#pragma unroll
    for (int rt = 0; rt < 4; rt++)
#pragma unroll
        for (int r = 0; r < 4; r++)
            inv[rt][r] = 1.0f / lb[qt * 128 + wr * 64 + rt * 16 + quad * 4 + r];

    __syncthreads();
    float* Ot = (float*)smem;   // 64 x 132 (rows 16B-aligned)
#pragma unroll
    for (int h = 0; h < 2; h++) {
        if (wr == h) {
#pragma unroll
            for (int rt = 0; rt < 4; rt++)
#pragma unroll
                for (int r = 0; r < 4; r++) {
                    const int rloc = rt * 16 + quad * 4 + r;
#pragma unroll
                    for (int ct = 0; ct < 4; ct++)
                        Ot[rloc * 132 + wc * 64 + ct * 16 + l16] = acc[rt][ct][r] * inv[rt][r];
                }
        }
        __syncthreads();
        const int row = tid >> 2, qq = tid & 3;
        const float* src = Ot + row * 132 + qq * 32;
        float* dst = Out + (size_t)(b * S_LEN + qt * 128 + h * 64 + row) * DM + dt * 128 + qq * 32;
#pragma unroll
        for (int i = 0; i < 8; i++)
            *(f32x4*)(dst + i * 4) = *(const f32x4*)(src + i * 4);
        __syncthreads();
    }
}

extern "C" void kernel_launch(void* const* d_in, const int* in_sizes, int n_in,
                              void* d_out, int out_size, void* d_ws, size_t ws_size,
                              hipStream_t stream)
{
    const float* Eq = (const float*)d_in[0];
    const float* Ek = (const float*)d_in[1];
    const float* Ev = (const float*)d_in[2];
    const float* Wq = (const float*)d_in[3];
    const float* bq = (const float*)d_in[4];
    const float* Wk = (const float*)d_in[5];
    const float* bk = (const float*)d_in[6];
    const float* Wv = (const float*)d_in[7];
    const float* bv = (const float*)d_in[8];
    const int* maskp = (const int*)d_in[9];
    float* Out = (float*)d_out;

    // ws layout (~103 MB):
    //  [Qb 16M][Kb 16M][Vtb 16M][Wqb 2M][Wkb 2M][Wvb 2M][lsum 1M][P 32M | Eb overlay 48M]
    char* ws = (char*)d_ws;
    const size_t SZ_QKV = (size_t)NB * S_LEN * DM * 2;
    const size_t SZ_W   = (size_t)DM * DM * 2;
    bf16* Qb  = (bf16*)(ws);
    bf16* Kb  = (bf16*)(ws + SZ_QKV);
    bf16* Vtb = (bf16*)(ws + 2 * SZ_QKV);
    bf16* Wqb = (bf16*)(ws + 3 * SZ_QKV);
    bf16* Wkb = (bf16*)(ws + 3 * SZ_QKV + SZ_W);
    bf16* Wvb = (bf16*)(ws + 3 * SZ_QKV + 2 * SZ_W);
    float* lsum = (float*)(ws + 3 * SZ_QKV + 3 * SZ_W);
    bf16* Pbuf = (bf16*)(ws + 3 * SZ_QKV + 3 * SZ_W + (1 << 20));
    bf16* Eqb = Pbuf;   // E bf16 staging overlays P (dead once proj completes)
    bf16* Ekb = Eqb + (size_t)NB * S_LEN * DM;
    bf16* Evb = Ekb + (size_t)NB * S_LEN * DM;

    hipMemsetAsync(lsum, 0, (size_t)NB * S_LEN * 4, stream);
    cvt3_kernel<<<dim3(512, 3), 256, 0, stream>>>(Wq, Wk, Wv, Wqb, Wkb, Wvb);
    cvt3_kernel<<<dim3(4096, 3), 256, 0, stream>>>(Eq, Ek, Ev, Eqb, Ekb, Evb);

    proj_kernel<<<1536, 256, 0, stream>>>(
        Eqb, Ekb, Evb, Wqb, Wkb, Wvb, bq, bk, bv, Qb, Kb, Vtb);

    qk_kernel<<<1024, 256, 0, stream>>>(Qb, Kb, maskp, Pbuf, lsum);
    pv_kernel<<<512, 256, 0, stream>>>(Pbuf, Vtb, lsum, maskp, Out);
}